// Round 12
// baseline (338.636 us; speedup 1.0000x reference)
//
#include <hip/hip_runtime.h>
#include <hip/hip_fp16.h>
#include <type_traits>

#define HH 128   // hidden size (both layers, and F_IN)

// ================= bucketed 2-phase counting sort (edge CSR + node CSR) =================
// bucket = key >> 8 (256 keys per bucket).  nbkt <= 512, payload < 2^23 required.
// part record: (payload << 8) | (key & 255)   -- 4 bytes

__global__ __launch_bounds__(256) void part_count_k(const int* __restrict__ key, int e,
                                                    int chunk, int nbkt, int nblk,
                                                    int* __restrict__ gcnt,
                                                    int* __restrict__ blkoff) {
  __shared__ int h[512];
  for (int i = threadIdx.x; i < nbkt; i += 256) h[i] = 0;
  __syncthreads();
  int start = blockIdx.x * chunk;
  int cnt = e - start; if (cnt > chunk) cnt = chunk;
  for (int i = threadIdx.x; i < cnt; i += 256)
    atomicAdd(&h[key[start + i] >> 8], 1);
  __syncthreads();
  for (int i = threadIdx.x; i < nbkt; i += 256) {
    int c = h[i];
    if (c) blkoff[(size_t)i * nblk + blockIdx.x] = atomicAdd(&gcnt[i], c);
  }
}

__global__ __launch_bounds__(512) void scan_bkt_k(const int* __restrict__ gcnt,
                                                  int* __restrict__ bktbase, int nbkt, int e) {
  __shared__ int sc[512];
  int tid = threadIdx.x;
  int v = (tid < nbkt) ? gcnt[tid] : 0;
  sc[tid] = v;
  __syncthreads();
  for (int off = 1; off < 512; off <<= 1) {
    int t = (tid >= off) ? sc[tid - off] : 0;
    __syncthreads();
    sc[tid] += t;
    __syncthreads();
  }
  if (tid < nbkt) bktbase[tid] = sc[tid] - v;
  if (tid == 0) bktbase[nbkt] = e;
}

// payload = src[i] (edge version)
__global__ __launch_bounds__(256) void part_scatter_k(const int* __restrict__ src,
                                                      const int* __restrict__ key, int e,
                                                      int chunk, int nbkt, int nblk,
                                                      const int* __restrict__ bktbase,
                                                      const int* __restrict__ blkoff,
                                                      int* __restrict__ part) {
  __shared__ int cur[512];
  for (int i = threadIdx.x; i < nbkt; i += 256)
    cur[i] = bktbase[i] + blkoff[(size_t)i * nblk + blockIdx.x];
  __syncthreads();
  int start = blockIdx.x * chunk;
  int cnt = e - start; if (cnt > chunk) cnt = chunk;
  for (int i = threadIdx.x; i < cnt; i += 256) {
    int d = key[start + i], s = src[start + i];
    int pos = atomicAdd(&cur[d >> 8], 1);
    part[pos] = (s << 8) | (d & 255);
  }
}

// payload = global index i (node version)
__global__ __launch_bounds__(256) void part_scatter_idx_k(const int* __restrict__ key, int e,
                                                          int chunk, int nbkt, int nblk,
                                                          const int* __restrict__ bktbase,
                                                          const int* __restrict__ blkoff,
                                                          int* __restrict__ part) {
  __shared__ int cur[512];
  for (int i = threadIdx.x; i < nbkt; i += 256)
    cur[i] = bktbase[i] + blkoff[(size_t)i * nblk + blockIdx.x];
  __syncthreads();
  int start = blockIdx.x * chunk;
  int cnt = e - start; if (cnt > chunk) cnt = chunk;
  for (int i = threadIdx.x; i < cnt; i += 256) {
    int d = key[start + i];
    int pos = atomicAdd(&cur[d >> 8], 1);
    part[pos] = ((start + i) << 8) | (d & 255);
  }
}

// Per bucket (256 keys): LDS hist + scan -> rowptr, optional dinv, payload list.
__global__ __launch_bounds__(256) void bucket_csr_k(const int* __restrict__ part,
                                                    const int* __restrict__ bktbase,
                                                    int* __restrict__ rowptr,
                                                    float* __restrict__ dinv,
                                                    int* __restrict__ esrc,
                                                    int n, int e, int nbkt) {
  __shared__ int hist[256];
  __shared__ int sc[256];
  __shared__ int cur[256];
  int tid = threadIdx.x;
  int b = blockIdx.x;
  int dstbase = b << 8;
  int nloc = n - dstbase; if (nloc > 256) nloc = 256;
  int beg = bktbase[b], bend = bktbase[b + 1];

  hist[tid] = 0;
  __syncthreads();
  for (int j = beg + tid; j < bend; j += 256)
    atomicAdd(&hist[part[j] & 255], 1);
  __syncthreads();
  int v = hist[tid];
  sc[tid] = v;
  __syncthreads();
  for (int off = 1; off < 256; off <<= 1) {
    int t = (tid >= off) ? sc[tid - off] : 0;
    __syncthreads();
    sc[tid] += t;
    __syncthreads();
  }
  int excl = sc[tid] - v;
  if (tid < nloc) {
    rowptr[dstbase + tid] = beg + excl;
    cur[tid] = beg + excl;
    if (dinv) dinv[dstbase + tid] = rsqrtf((float)v + 1.0f);
  }
  __syncthreads();
  for (int j = beg + tid; j < bend; j += 256) {
    int p = part[j];
    int pos = atomicAdd(&cur[p & 255], 1);
    esrc[pos] = p >> 8;
  }
  if (b == nbkt - 1 && tid == 0) rowptr[n] = e;
}

// ========== GEMM v5: 2-phase K staging, quarter-row threads; input fp32 or fp16 ==========
// OUT16: write scale(i)*(A@W) as fp16 (half2-packed); else fp32.
template <typename TIN, bool OUT16>
__global__ __launch_bounds__(256) void gemm128_v5(const TIN* __restrict__ A,
                                                  const float* __restrict__ W,
                                                  const float* __restrict__ dscale,
                                                  void* __restrict__ out, int n) {
  __shared__ float As[64][65];
  const int tid = threadIdx.x;
  const int rbase = blockIdx.x * 64;
  const int vrows = (n - rbase) < 64 ? (n - rbase) : 64;

  const int r = tid & 63;
  const int q = __builtin_amdgcn_readfirstlane(tid >> 6);
  const float* Wq = W + q * 32;

  float4 acc[8];
  #pragma unroll
  for (int c = 0; c < 8; ++c) acc[c] = make_float4(0.f, 0.f, 0.f, 0.f);

  #pragma unroll
  for (int ph = 0; ph < 2; ++ph) {
    if (ph) __syncthreads();
    if (std::is_same<TIN, __half>::value) {
      #pragma unroll
      for (int j = 0; j < 2; ++j) {
        int f = tid + 256 * j;
        int rr = f >> 3, c8 = f & 7;
        uint4 u = make_uint4(0u, 0u, 0u, 0u);
        if (rr < vrows)
          u = ((const uint4*)((const __half*)A + (size_t)(rbase + rr) * HH + ph * 64))[c8];
        __half2* hp = (__half2*)&u;
        #pragma unroll
        for (int t = 0; t < 4; ++t) {
          float2 f2 = __half22float2(hp[t]);
          As[rr][c8 * 8 + 2 * t + 0] = f2.x;
          As[rr][c8 * 8 + 2 * t + 1] = f2.y;
        }
      }
    } else {
      #pragma unroll
      for (int j = 0; j < 4; ++j) {
        int f = tid + 256 * j;
        int rr = f >> 4, c4 = f & 15;
        float4 v = (rr < vrows)
            ? ((const float4*)((const float*)A + (size_t)(rbase + rr) * HH + ph * 64))[c4]
            : make_float4(0.f, 0.f, 0.f, 0.f);
        As[rr][c4 * 4 + 0] = v.x;
        As[rr][c4 * 4 + 1] = v.y;
        As[rr][c4 * 4 + 2] = v.z;
        As[rr][c4 * 4 + 3] = v.w;
      }
    }
    __syncthreads();

    #pragma unroll 4
    for (int kk = 0; kk < 64; ++kk) {
      float a = As[r][kk];
      const float4* Wr = (const float4*)(Wq + (size_t)(ph * 64 + kk) * HH);
      #pragma unroll
      for (int c = 0; c < 8; ++c) {
        float4 w = Wr[c];
        acc[c].x += a * w.x; acc[c].y += a * w.y;
        acc[c].z += a * w.z; acc[c].w += a * w.w;
      }
    }
  }

  int row = rbase + r;
  if (row < n) {
    float s = dscale ? dscale[row] : 1.0f;
    if (OUT16) {
      uint2* o = (uint2*)((__half*)out + (size_t)row * HH) + q * 8;
      #pragma unroll
      for (int c = 0; c < 8; ++c) {
        __half2 h0 = __float22half2_rn(make_float2(acc[c].x * s, acc[c].y * s));
        __half2 h1 = __float22half2_rn(make_float2(acc[c].z * s, acc[c].w * s));
        uint2 u;
        u.x = *reinterpret_cast<unsigned*>(&h0);
        u.y = *reinterpret_cast<unsigned*>(&h1);
        o[c] = u;
      }
    } else {
      float4* o = (float4*)((float*)out + (size_t)row * HH + q * 32);
      #pragma unroll
      for (int c = 0; c < 8; ++c) {
        acc[c].x *= s; acc[c].y *= s; acc[c].z *= s; acc[c].w *= s;
        o[c] = acc[c];
      }
    }
  }
}

// ==== gather conv v2: 4 edges per wave (16 lanes x uint4 = full 256B row per load inst) ====
// h[d] = relu(bias + dinv[d]*(self' + sum xw16[s])), written fp16.
__global__ __launch_bounds__(256) void gather16b_k(const __half* __restrict__ xw16,
                                                   const int* __restrict__ rowptr,
                                                   const int* __restrict__ esrc,
                                                   const float* __restrict__ dinv,
                                                   const float* __restrict__ bias,
                                                   __half* __restrict__ h, int n) {
  int wid = (int)((blockIdx.x * (size_t)blockDim.x + threadIdx.x) >> 6);
  int lane = threadIdx.x & 63;
  if (wid >= n) return;
  int g = lane >> 4, l16 = lane & 15;
  int beg = rowptr[wid], end = rowptr[wid + 1];
  const uint4* base = (const uint4*)xw16 + l16;   // row = 16 uint4
  float a[8];
  #pragma unroll
  for (int t = 0; t < 8; ++t) a[t] = 0.f;

  for (int j0 = beg; j0 < end; j0 += 64) {
    int myj = j0 + lane;
    int sv = (myj < end) ? esrc[myj] : 0;
    int cnt = end - j0; if (cnt > 64) cnt = 64;
    #pragma unroll 2
    for (int k = 0; k < cnt; k += 8) {
      int i0 = k + 2 * g;          // group g handles edges i0, i0+1
      int i1 = i0 + 1;
      int s0 = __shfl(sv, i0);
      int s1 = __shfl(sv, i1);
      if (i0 < cnt) {
        uint4 u = base[(size_t)(unsigned)s0 << 4];
        __half2* hp = (__half2*)&u;
        #pragma unroll
        for (int t = 0; t < 4; ++t) {
          float2 f2 = __half22float2(hp[t]);
          a[2 * t] += f2.x; a[2 * t + 1] += f2.y;
        }
      }
      if (i1 < cnt) {
        uint4 u = base[(size_t)(unsigned)s1 << 4];
        __half2* hp = (__half2*)&u;
        #pragma unroll
        for (int t = 0; t < 4; ++t) {
          float2 f2 = __half22float2(hp[t]);
          a[2 * t] += f2.x; a[2 * t + 1] += f2.y;
        }
      }
    }
  }
  // reduce across the 4 groups (lanes differing in bits 4,5)
  #pragma unroll
  for (int t = 0; t < 8; ++t) {
    a[t] += __shfl_xor(a[t], 16);
    a[t] += __shfl_xor(a[t], 32);
  }
  if (g == 0) {
    uint4 u = base[(size_t)(unsigned)wid << 4];   // self term
    __half2* hp = (__half2*)&u;
    float di = dinv[wid];
    float4 b0 = ((const float4*)bias)[l16 * 2];
    float4 b1 = ((const float4*)bias)[l16 * 2 + 1];
    float bb[8] = {b0.x, b0.y, b0.z, b0.w, b1.x, b1.y, b1.z, b1.w};
    uint4 w;
    __half2* wp = (__half2*)&w;
    #pragma unroll
    for (int t = 0; t < 4; ++t) {
      float2 s2 = __half22float2(hp[t]);
      float o0 = fmaxf(bb[2 * t]     + di * (a[2 * t]     + s2.x), 0.f);
      float o1 = fmaxf(bb[2 * t + 1] + di * (a[2 * t + 1] + s2.y), 0.f);
      wp[t] = __float22half2_rn(make_float2(o0, o1));
    }
    ((uint4*)h)[((size_t)wid << 4) + l16] = w;
  }
}

// ====== pool (fp16 -> fp16): z[g] = mean over members; 16-lane subgroup, uint4/lane ======
__global__ __launch_bounds__(256) void pool16_k(const __half* __restrict__ h2,
                                                const int* __restrict__ rowptr,
                                                const int* __restrict__ nodelist,
                                                __half* __restrict__ z, int n) {
  int gid = blockIdx.x * blockDim.x + threadIdx.x;
  int g = gid >> 4, l16 = gid & 15;
  if (g >= n) return;
  int beg = rowptr[g], end = rowptr[g + 1];
  const uint4* h4 = (const uint4*)h2;   // row = 16 uint4
  float a[8];
  #pragma unroll
  for (int t = 0; t < 8; ++t) a[t] = 0.f;
  for (int j = beg; j < end; ++j) {
    int m = nodelist[j];
    uint4 u = h4[((size_t)m << 4) + l16];
    __half2* hp = (__half2*)&u;
    #pragma unroll
    for (int t = 0; t < 4; ++t) {
      float2 f2 = __half22float2(hp[t]);
      a[2 * t + 0] += f2.x;
      a[2 * t + 1] += f2.y;
    }
  }
  float inv = 1.0f / fmaxf((float)(end - beg), 1.0f);
  uint4 w;
  __half2* wp = (__half2*)&w;
  #pragma unroll
  for (int t = 0; t < 4; ++t)
    wp[t] = __float22half2_rn(make_float2(a[2 * t] * inv, a[2 * t + 1] * inv));
  ((uint4*)z)[((size_t)g << 4) + l16] = w;
}

// ====== decode (fp16 z): logits[e] = dot(z[a], z[b]); 16 lanes per edge, uint4/lane ======
__global__ __launch_bounds__(256) void decode16_k(const __half* __restrict__ z,
                                                  const int* __restrict__ pos,
                                                  const int* __restrict__ neg,
                                                  float* __restrict__ out, int ep) {
  int gid = blockIdx.x * blockDim.x + threadIdx.x;
  int edge = gid >> 4, l16 = gid & 15;
  if (edge >= 2 * ep) return;
  int a, b;
  if (edge < ep) { a = pos[edge];      b = pos[ep + edge]; }
  else           { int t = edge - ep; a = neg[t]; b = neg[ep + t]; }
  const uint4* z4 = (const uint4*)z;
  uint4 ua = z4[((size_t)a << 4) + l16];
  uint4 ub = z4[((size_t)b << 4) + l16];
  __half2* ha = (__half2*)&ua;
  __half2* hb = (__half2*)&ub;
  float dot = 0.f;
  #pragma unroll
  for (int t = 0; t < 4; ++t) {
    float2 fa = __half22float2(ha[t]);
    float2 fb = __half22float2(hb[t]);
    dot += fa.x * fb.x + fa.y * fb.y;
  }
  #pragma unroll
  for (int off = 8; off > 0; off >>= 1) dot += __shfl_xor(dot, off);
  if (l16 == 0) out[edge] = dot;
}

// ================= fallback path (small ws): atomic version =================
__global__ void fill_deg_k(float* __restrict__ deg, int n) {
  int i = blockIdx.x * blockDim.x + threadIdx.x;
  if (i < n) deg[i] = 1.0f;
}
__global__ void accum_deg_k(const int* __restrict__ dst, float* __restrict__ deg, int e) {
  int i = blockIdx.x * blockDim.x + threadIdx.x;
  if (i < e) atomicAdd(&deg[dst[i]], 1.0f);
}
__global__ void dinv_k(float* __restrict__ deg, int n) {
  int i = blockIdx.x * blockDim.x + threadIdx.x;
  if (i < n) deg[i] = rsqrtf(deg[i]);
}
__global__ void init_h_k(const float* __restrict__ xw, const float* __restrict__ bias,
                         const float* __restrict__ dinv, float* __restrict__ h, int n) {
  int gid = blockIdx.x * blockDim.x + threadIdx.x;
  int node = gid >> 5, c4 = gid & 31;
  if (node >= n) return;
  float di = dinv[node];
  float nm = di * di;
  float4 v = ((const float4*)(xw + (size_t)node * HH))[c4];
  float4 b = ((const float4*)bias)[c4];
  ((float4*)(h + (size_t)node * HH))[c4] =
      make_float4(b.x + nm * v.x, b.y + nm * v.y, b.z + nm * v.z, b.w + nm * v.w);
}
__global__ void scatter_k(const float* __restrict__ xw, float* __restrict__ h,
                          const float* __restrict__ dinv, const int* __restrict__ src,
                          const int* __restrict__ dst, int e) {
  int gid = blockIdx.x * blockDim.x + threadIdx.x;
  int edge = gid >> 5, lane = gid & 31;
  if (edge >= e) return;
  int s = src[edge], d = dst[edge];
  float norm = dinv[s] * dinv[d];
  float4 v = ((const float4*)(xw + (size_t)s * HH))[lane];
  float* o = h + (size_t)d * HH + lane * 4;
  atomicAdd(o + 0, norm * v.x);
  atomicAdd(o + 1, norm * v.y);
  atomicAdd(o + 2, norm * v.z);
  atomicAdd(o + 3, norm * v.w);
}
__global__ void relu_k(float4* __restrict__ h, int n4) {
  int i = blockIdx.x * blockDim.x + threadIdx.x;
  if (i < n4) {
    float4 v = h[i];
    v.x = fmaxf(v.x, 0.f); v.y = fmaxf(v.y, 0.f);
    v.z = fmaxf(v.z, 0.f); v.w = fmaxf(v.w, 0.f);
    h[i] = v;
  }
}
__global__ void pool_accum_k(const float* __restrict__ h, const int* __restrict__ dict,
                             float* __restrict__ z, float* __restrict__ cnt, int n) {
  int gid = blockIdx.x * blockDim.x + threadIdx.x;
  int node = gid >> 5, lane = gid & 31;
  if (node >= n) return;
  int d = dict[node];
  float4 v = ((const float4*)(h + (size_t)node * HH))[lane];
  float* o = z + (size_t)d * HH + lane * 4;
  atomicAdd(o + 0, v.x); atomicAdd(o + 1, v.y);
  atomicAdd(o + 2, v.z); atomicAdd(o + 3, v.w);
  if (lane == 0) atomicAdd(&cnt[d], 1.0f);
}
__global__ void pool_div_k(float* __restrict__ z, const float* __restrict__ cnt, int n) {
  int gid = blockIdx.x * blockDim.x + threadIdx.x;
  int node = gid >> 5, lane = gid & 31;
  if (node >= n) return;
  float inv = 1.0f / fmaxf(cnt[node], 1.0f);
  float4* p = (float4*)(z + (size_t)node * HH) + lane;
  float4 v = *p;
  v.x *= inv; v.y *= inv; v.z *= inv; v.w *= inv;
  *p = v;
}
__global__ void decode_k(const float* __restrict__ z, const int* __restrict__ pos,
                         const int* __restrict__ neg, float* __restrict__ out, int ep) {
  int gid = blockIdx.x * blockDim.x + threadIdx.x;
  int edge = gid >> 5, lane = gid & 31;
  if (edge >= 2 * ep) return;
  int a, b;
  if (edge < ep) { a = pos[edge];      b = pos[ep + edge]; }
  else           { a = neg[edge - ep]; b = neg[edge]; }
  const float4* za = (const float4*)(z + (size_t)a * HH);
  const float4* zb = (const float4*)(z + (size_t)b * HH);
  float4 va = za[lane], vb = zb[lane];
  float dot = va.x * vb.x + va.y * vb.y + va.z * vb.z + va.w * vb.w;
  #pragma unroll
  for (int off = 16; off > 0; off >>= 1) dot += __shfl_xor(dot, off);
  if (lane == 0) out[edge] = dot;
}

// ================= host launch =================
extern "C" void kernel_launch(void* const* d_in, const int* in_sizes, int n_in,
                              void* d_out, int out_size, void* d_ws, size_t ws_size,
                              hipStream_t stream) {
  const float* x  = (const float*)d_in[0];
  const float* W1 = (const float*)d_in[1];
  const float* b1 = (const float*)d_in[2];
  const float* W2 = (const float*)d_in[3];
  const float* b2 = (const float*)d_in[4];
  const int* ei   = (const int*)d_in[5];
  const int* dict = (const int*)d_in[6];
  const int* pe   = (const int*)d_in[7];
  const int* ne   = (const int*)d_in[8];

  const int n  = in_sizes[0] / HH;   // 100000
  const int e  = in_sizes[5] / 2;    // 1.6M
  const int ep = in_sizes[7] / 2;    // 200000
  const int* src = ei;
  const int* dst = ei + e;

  const size_t nf = (size_t)n * HH;
  const int nbkt  = (n + 255) >> 8;                 // 391
  const int CHE   = 16384, CHN = 2048;
  const int nblkE = (e + CHE - 1) / CHE;            // 98
  const int nblkN = (n + CHN - 1) / CHN;            // 49

  float*  p0     = (float*)d_ws;
  float*  bufF   = p0;
  __half* xw16   = (__half*)(p0 + nf);
  float*  dinv   = p0 + nf + nf / 2;
  int*    rowptr = (int*)(dinv + n);
  int*    tmp    = rowptr + (n + 1);
  int*    esrc   = tmp + n;
  int*    bsum   = esrc + e;
  int*    gcnt   = bsum + 256;
  int*    bktbase = gcnt + nbkt;
  size_t need = (nf + nf / 2 + n) * sizeof(float) +
                (size_t)(3 * n + 1 + e + 256 + 2 * nbkt + 1) * sizeof(int);

  int* partE   = (int*)bufF;               // e ints (6.4 MB) <= nf floats
  int* blkoffE = (int*)xw16;               // nbkt*nblkE ints <= nf halves
  int* partN   = (int*)(bufF + nf / 2);    // n ints, upper half of bufF
  int* blkoffN = partN + n;                // nbkt*nblkN ints

  const int nb    = (n + 255) / 256;
  const int nb16  = (int)(((size_t)n * 16 + 255) / 256);
  const int nb32  = (int)(((size_t)n * 32 + 255) / 256);
  const int nb64  = (int)(((size_t)n * 64 + 255) / 256);
  const int gemb  = (n + 63) / 64;
  const int deb16 = (int)(((size_t)2 * ep * 16 + 255) / 256);

  bool fast = (ws_size >= need) && (nbkt <= 512) && (n < (1 << 23)) &&
              ((size_t)e <= nf) && ((size_t)nbkt * nblkE * 2 <= nf) &&
              ((size_t)(n + (size_t)nbkt * nblkN) * 2 <= nf);

  if (fast) {
    // ---- edge CSR (by dst) + dinv: bucketed 2-phase sort (packed records) ----
    hipMemsetAsync(gcnt, 0, (size_t)nbkt * sizeof(int), stream);
    part_count_k<<<nblkE, 256, 0, stream>>>(dst, e, CHE, nbkt, nblkE, gcnt, blkoffE);
    scan_bkt_k<<<1, 512, 0, stream>>>(gcnt, bktbase, nbkt, e);
    part_scatter_k<<<nblkE, 256, 0, stream>>>(src, dst, e, CHE, nbkt, nblkE, bktbase, blkoffE, partE);
    bucket_csr_k<<<nbkt, 256, 0, stream>>>(partE, bktbase, rowptr, dinv, esrc, n, e, nbkt);

    // ---- conv1: xw16 = fp16(dinv * x@W1);  h1 fp16 in lower bufF ----
    gemm128_v5<float, true><<<gemb, 256, 0, stream>>>(x, W1, dinv, xw16, n);
    __half* h1_16 = (__half*)bufF;
    gather16b_k<<<nb64, 256, 0, stream>>>(xw16, rowptr, esrc, dinv, b1, h1_16, n);
    // ---- conv2: xw16 = fp16(dinv * h1@W2);  h2 fp16 overwrites h1 region ----
    gemm128_v5<__half, true><<<gemb, 256, 0, stream>>>(h1_16, W2, dinv, xw16, n);
    __half* h2_16 = (__half*)bufF;
    gather16b_k<<<nb64, 256, 0, stream>>>(xw16, rowptr, esrc, dinv, b2, h2_16, n);
    // xw16 dead -> becomes z; upper half of bufF free -> partN

    // ---- node CSR (by dict): bucketed sort (packed records, chunk=2048) ----
    hipMemsetAsync(gcnt, 0, (size_t)nbkt * sizeof(int), stream);
    part_count_k<<<nblkN, 256, 0, stream>>>(dict, n, CHN, nbkt, nblkN, gcnt, blkoffN);
    scan_bkt_k<<<1, 512, 0, stream>>>(gcnt, bktbase, nbkt, n);
    part_scatter_idx_k<<<nblkN, 256, 0, stream>>>(dict, n, CHN, nbkt, nblkN, bktbase, blkoffN, partN);
    bucket_csr_k<<<nbkt, 256, 0, stream>>>(partN, bktbase, rowptr, nullptr, esrc, n, n, nbkt);
    // rowptr = group rowptr, esrc = nodelist

    // ---- pool (fp16 z) then plain dot decode ----
    __half* z16 = xw16;
    pool16_k<<<nb16, 256, 0, stream>>>(h2_16, rowptr, esrc, z16, n);
    decode16_k<<<deb16, 256, 0, stream>>>(z16, pe, ne, (float*)d_out, ep);
  } else {
    // ---- fallback: atomic path (bufA, bufB, dinv2, cnt), all fp32 ----
    float* bufA  = (float*)d_ws;
    float* bufB  = bufA + nf;
    float* dinv2 = bufB + nf;
    float* cnt   = dinv2 + n;
    fill_deg_k<<<nb, 256, 0, stream>>>(dinv2, n);
    accum_deg_k<<<(e + 255) / 256, 256, 0, stream>>>(dst, dinv2, e);
    dinv_k<<<nb, 256, 0, stream>>>(dinv2, n);

    gemm128_v5<float, false><<<gemb, 256, 0, stream>>>(x, W1, nullptr, bufA, n);
    init_h_k<<<nb32, 256, 0, stream>>>(bufA, b1, dinv2, bufB, n);
    scatter_k<<<(int)(((size_t)e * 32 + 255) / 256), 256, 0, stream>>>(bufA, bufB, dinv2, src, dst, e);
    relu_k<<<nb32, 256, 0, stream>>>((float4*)bufB, n * 32);

    gemm128_v5<float, false><<<gemb, 256, 0, stream>>>(bufB, W2, nullptr, bufA, n);
    init_h_k<<<nb32, 256, 0, stream>>>(bufA, b2, dinv2, bufB, n);
    scatter_k<<<(int)(((size_t)e * 32 + 255) / 256), 256, 0, stream>>>(bufA, bufB, dinv2, src, dst, e);
    relu_k<<<nb32, 256, 0, stream>>>((float4*)bufB, n * 32);

    hipMemsetAsync(bufA, 0, nf * sizeof(float), stream);
    hipMemsetAsync(cnt, 0, (size_t)n * sizeof(float), stream);
    pool_accum_k<<<nb32, 256, 0, stream>>>(bufB, dict, bufA, cnt, n);
    pool_div_k<<<nb32, 256, 0, stream>>>(bufA, cnt, n);
    decode_k<<<(int)(((size_t)2 * ep * 32 + 255) / 256), 256, 0, stream>>>(
        bufA, pe, ne, (float*)d_out, ep);
  }
}

// Round 13
// 333.993 us; speedup vs baseline: 1.0139x; 1.0139x over previous
//
#include <hip/hip_runtime.h>
#include <hip/hip_fp16.h>
#include <type_traits>

#define HH 128   // hidden size (both layers, and F_IN)

// ================= bucketed 2-phase counting sort (edge CSR + node CSR) =================
// bucket = key >> 8 (256 keys per bucket).  nbkt <= 512, payload < 2^23 required.
// part record: (payload << 8) | (key & 255)   -- 4 bytes

__global__ __launch_bounds__(256) void part_count_k(const int* __restrict__ key, int e,
                                                    int chunk, int nbkt, int nblk,
                                                    int* __restrict__ gcnt,
                                                    int* __restrict__ blkoff) {
  __shared__ int h[512];
  for (int i = threadIdx.x; i < nbkt; i += 256) h[i] = 0;
  __syncthreads();
  int start = blockIdx.x * chunk;
  int cnt = e - start; if (cnt > chunk) cnt = chunk;
  for (int i = threadIdx.x; i < cnt; i += 256)
    atomicAdd(&h[key[start + i] >> 8], 1);
  __syncthreads();
  for (int i = threadIdx.x; i < nbkt; i += 256) {
    int c = h[i];
    if (c) blkoff[(size_t)i * nblk + blockIdx.x] = atomicAdd(&gcnt[i], c);
  }
}

__global__ __launch_bounds__(512) void scan_bkt_k(const int* __restrict__ gcnt,
                                                  int* __restrict__ bktbase, int nbkt, int e) {
  __shared__ int sc[512];
  int tid = threadIdx.x;
  int v = (tid < nbkt) ? gcnt[tid] : 0;
  sc[tid] = v;
  __syncthreads();
  for (int off = 1; off < 512; off <<= 1) {
    int t = (tid >= off) ? sc[tid - off] : 0;
    __syncthreads();
    sc[tid] += t;
    __syncthreads();
  }
  if (tid < nbkt) bktbase[tid] = sc[tid] - v;
  if (tid == 0) bktbase[nbkt] = e;
}

// payload = src[i] (edge version)
__global__ __launch_bounds__(256) void part_scatter_k(const int* __restrict__ src,
                                                      const int* __restrict__ key, int e,
                                                      int chunk, int nbkt, int nblk,
                                                      const int* __restrict__ bktbase,
                                                      const int* __restrict__ blkoff,
                                                      int* __restrict__ part) {
  __shared__ int cur[512];
  for (int i = threadIdx.x; i < nbkt; i += 256)
    cur[i] = bktbase[i] + blkoff[(size_t)i * nblk + blockIdx.x];
  __syncthreads();
  int start = blockIdx.x * chunk;
  int cnt = e - start; if (cnt > chunk) cnt = chunk;
  for (int i = threadIdx.x; i < cnt; i += 256) {
    int d = key[start + i], s = src[start + i];
    int pos = atomicAdd(&cur[d >> 8], 1);
    part[pos] = (s << 8) | (d & 255);
  }
}

// payload = global index i (node version)
__global__ __launch_bounds__(256) void part_scatter_idx_k(const int* __restrict__ key, int e,
                                                          int chunk, int nbkt, int nblk,
                                                          const int* __restrict__ bktbase,
                                                          const int* __restrict__ blkoff,
                                                          int* __restrict__ part) {
  __shared__ int cur[512];
  for (int i = threadIdx.x; i < nbkt; i += 256)
    cur[i] = bktbase[i] + blkoff[(size_t)i * nblk + blockIdx.x];
  __syncthreads();
  int start = blockIdx.x * chunk;
  int cnt = e - start; if (cnt > chunk) cnt = chunk;
  for (int i = threadIdx.x; i < cnt; i += 256) {
    int d = key[start + i];
    int pos = atomicAdd(&cur[d >> 8], 1);
    part[pos] = ((start + i) << 8) | (d & 255);
  }
}

// Per bucket (256 keys): LDS hist + scan -> rowptr, optional dinv, payload list.
__global__ __launch_bounds__(256) void bucket_csr_k(const int* __restrict__ part,
                                                    const int* __restrict__ bktbase,
                                                    int* __restrict__ rowptr,
                                                    float* __restrict__ dinv,
                                                    int* __restrict__ esrc,
                                                    int n, int e, int nbkt) {
  __shared__ int hist[256];
  __shared__ int sc[256];
  __shared__ int cur[256];
  int tid = threadIdx.x;
  int b = blockIdx.x;
  int dstbase = b << 8;
  int nloc = n - dstbase; if (nloc > 256) nloc = 256;
  int beg = bktbase[b], bend = bktbase[b + 1];

  hist[tid] = 0;
  __syncthreads();
  for (int j = beg + tid; j < bend; j += 256)
    atomicAdd(&hist[part[j] & 255], 1);
  __syncthreads();
  int v = hist[tid];
  sc[tid] = v;
  __syncthreads();
  for (int off = 1; off < 256; off <<= 1) {
    int t = (tid >= off) ? sc[tid - off] : 0;
    __syncthreads();
    sc[tid] += t;
    __syncthreads();
  }
  int excl = sc[tid] - v;
  if (tid < nloc) {
    rowptr[dstbase + tid] = beg + excl;
    cur[tid] = beg + excl;
    if (dinv) dinv[dstbase + tid] = rsqrtf((float)v + 1.0f);
  }
  __syncthreads();
  for (int j = beg + tid; j < bend; j += 256) {
    int p = part[j];
    int pos = atomicAdd(&cur[p & 255], 1);
    esrc[pos] = p >> 8;
  }
  if (b == nbkt - 1 && tid == 0) rowptr[n] = e;
}

// ========== GEMM v5: 2-phase K staging, quarter-row threads; input fp32 or fp16 ==========
// OUT16: write scale(i)*(A@W) as fp16 (half2-packed); else fp32.
template <typename TIN, bool OUT16>
__global__ __launch_bounds__(256) void gemm128_v5(const TIN* __restrict__ A,
                                                  const float* __restrict__ W,
                                                  const float* __restrict__ dscale,
                                                  void* __restrict__ out, int n) {
  __shared__ float As[64][65];
  const int tid = threadIdx.x;
  const int rbase = blockIdx.x * 64;
  const int vrows = (n - rbase) < 64 ? (n - rbase) : 64;

  const int r = tid & 63;
  const int q = __builtin_amdgcn_readfirstlane(tid >> 6);
  const float* Wq = W + q * 32;

  float4 acc[8];
  #pragma unroll
  for (int c = 0; c < 8; ++c) acc[c] = make_float4(0.f, 0.f, 0.f, 0.f);

  #pragma unroll
  for (int ph = 0; ph < 2; ++ph) {
    if (ph) __syncthreads();
    if (std::is_same<TIN, __half>::value) {
      #pragma unroll
      for (int j = 0; j < 2; ++j) {
        int f = tid + 256 * j;
        int rr = f >> 3, c8 = f & 7;
        uint4 u = make_uint4(0u, 0u, 0u, 0u);
        if (rr < vrows)
          u = ((const uint4*)((const __half*)A + (size_t)(rbase + rr) * HH + ph * 64))[c8];
        __half2* hp = (__half2*)&u;
        #pragma unroll
        for (int t = 0; t < 4; ++t) {
          float2 f2 = __half22float2(hp[t]);
          As[rr][c8 * 8 + 2 * t + 0] = f2.x;
          As[rr][c8 * 8 + 2 * t + 1] = f2.y;
        }
      }
    } else {
      #pragma unroll
      for (int j = 0; j < 4; ++j) {
        int f = tid + 256 * j;
        int rr = f >> 4, c4 = f & 15;
        float4 v = (rr < vrows)
            ? ((const float4*)((const float*)A + (size_t)(rbase + rr) * HH + ph * 64))[c4]
            : make_float4(0.f, 0.f, 0.f, 0.f);
        As[rr][c4 * 4 + 0] = v.x;
        As[rr][c4 * 4 + 1] = v.y;
        As[rr][c4 * 4 + 2] = v.z;
        As[rr][c4 * 4 + 3] = v.w;
      }
    }
    __syncthreads();

    #pragma unroll 4
    for (int kk = 0; kk < 64; ++kk) {
      float a = As[r][kk];
      const float4* Wr = (const float4*)(Wq + (size_t)(ph * 64 + kk) * HH);
      #pragma unroll
      for (int c = 0; c < 8; ++c) {
        float4 w = Wr[c];
        acc[c].x += a * w.x; acc[c].y += a * w.y;
        acc[c].z += a * w.z; acc[c].w += a * w.w;
      }
    }
  }

  int row = rbase + r;
  if (row < n) {
    float s = dscale ? dscale[row] : 1.0f;
    if (OUT16) {
      uint2* o = (uint2*)((__half*)out + (size_t)row * HH) + q * 8;
      #pragma unroll
      for (int c = 0; c < 8; ++c) {
        __half2 h0 = __float22half2_rn(make_float2(acc[c].x * s, acc[c].y * s));
        __half2 h1 = __float22half2_rn(make_float2(acc[c].z * s, acc[c].w * s));
        uint2 u;
        u.x = *reinterpret_cast<unsigned*>(&h0);
        u.y = *reinterpret_cast<unsigned*>(&h1);
        o[c] = u;
      }
    } else {
      float4* o = (float4*)((float*)out + (size_t)row * HH + q * 32);
      #pragma unroll
      for (int c = 0; c < 8; ++c) {
        acc[c].x *= s; acc[c].y *= s; acc[c].z *= s; acc[c].w *= s;
        o[c] = acc[c];
      }
    }
  }
}

// ==== gather conv (fp16 messages): h[d]=relu(b+dinv[d]*(self'+sum xw16[s])), h fp16 ====
// R11-proven structure: 2 edges per wave (32 lanes x uint2 per row).
__global__ __launch_bounds__(256) void gather16_k(const __half* __restrict__ xw16,
                                                  const int* __restrict__ rowptr,
                                                  const int* __restrict__ esrc,
                                                  const float* __restrict__ dinv,
                                                  const float* __restrict__ bias,
                                                  __half* __restrict__ h, int n) {
  int wid = (int)((blockIdx.x * (size_t)blockDim.x + threadIdx.x) >> 6);
  int lane = threadIdx.x & 63;
  if (wid >= n) return;
  int beg = rowptr[wid], end = rowptr[wid + 1];
  int half = lane >> 5, l32 = lane & 31;
  const uint2* base = (const uint2*)xw16 + l32;   // row = 32 uint2
  float4 acc = make_float4(0.f, 0.f, 0.f, 0.f);

  for (int j0 = beg; j0 < end; j0 += 64) {
    int myj = j0 + lane;
    int sv = (myj < end) ? esrc[myj] : 0;
    int cnt = end - j0; if (cnt > 64) cnt = 64;
    int k = 0;
    for (; k + 8 <= cnt; k += 8) {
      #pragma unroll
      for (int p = 0; p < 4; ++p) {
        int sa = __builtin_amdgcn_readlane(sv, k + 2 * p);
        int sb = __builtin_amdgcn_readlane(sv, k + 2 * p + 1);
        unsigned off = (unsigned)(half ? sb : sa) << 5;
        uint2 u = base[off];
        float2 f0 = __half22float2(*reinterpret_cast<__half2*>(&u.x));
        float2 f1 = __half22float2(*reinterpret_cast<__half2*>(&u.y));
        acc.x += f0.x; acc.y += f0.y; acc.z += f1.x; acc.w += f1.y;
      }
    }
    for (; k + 2 <= cnt; k += 2) {
      int sa = __builtin_amdgcn_readlane(sv, k);
      int sb = __builtin_amdgcn_readlane(sv, k + 1);
      unsigned off = (unsigned)(half ? sb : sa) << 5;
      uint2 u = base[off];
      float2 f0 = __half22float2(*reinterpret_cast<__half2*>(&u.x));
      float2 f1 = __half22float2(*reinterpret_cast<__half2*>(&u.y));
      acc.x += f0.x; acc.y += f0.y; acc.z += f1.x; acc.w += f1.y;
    }
    if (k < cnt) {
      int sa = __builtin_amdgcn_readlane(sv, k);
      if (half == 0) {
        uint2 u = base[(unsigned)sa << 5];
        float2 f0 = __half22float2(*reinterpret_cast<__half2*>(&u.x));
        float2 f1 = __half22float2(*reinterpret_cast<__half2*>(&u.y));
        acc.x += f0.x; acc.y += f0.y; acc.z += f1.x; acc.w += f1.y;
      }
    }
  }
  acc.x += __shfl_xor(acc.x, 32);
  acc.y += __shfl_xor(acc.y, 32);
  acc.z += __shfl_xor(acc.z, 32);
  acc.w += __shfl_xor(acc.w, 32);
  if (half == 0) {
    uint2 u = base[(unsigned)wid << 5];
    float2 s0 = __half22float2(*reinterpret_cast<__half2*>(&u.x));
    float2 s1 = __half22float2(*reinterpret_cast<__half2*>(&u.y));
    float di = dinv[wid];
    float4 bb = ((const float4*)bias)[l32];
    float o0 = fmaxf(bb.x + di * (acc.x + s0.x), 0.f);
    float o1 = fmaxf(bb.y + di * (acc.y + s0.y), 0.f);
    float o2 = fmaxf(bb.z + di * (acc.z + s1.x), 0.f);
    float o3 = fmaxf(bb.w + di * (acc.w + s1.y), 0.f);
    __half2 p0 = __float22half2_rn(make_float2(o0, o1));
    __half2 p1 = __float22half2_rn(make_float2(o2, o3));
    uint2 w;
    w.x = *reinterpret_cast<unsigned*>(&p0);
    w.y = *reinterpret_cast<unsigned*>(&p1);
    ((uint2*)h)[((size_t)wid << 5) + l32] = w;
  }
}

// ====== pool (fp16 -> fp16): z[g] = mean over members; 16-lane subgroup, uint4/lane ======
__global__ __launch_bounds__(256) void pool16_k(const __half* __restrict__ h2,
                                                const int* __restrict__ rowptr,
                                                const int* __restrict__ nodelist,
                                                __half* __restrict__ z, int n) {
  int gid = blockIdx.x * blockDim.x + threadIdx.x;
  int g = gid >> 4, l16 = gid & 15;
  if (g >= n) return;
  int beg = rowptr[g], end = rowptr[g + 1];
  const uint4* h4 = (const uint4*)h2;   // row = 16 uint4
  float a[8];
  #pragma unroll
  for (int t = 0; t < 8; ++t) a[t] = 0.f;
  for (int j = beg; j < end; ++j) {
    int m = nodelist[j];
    uint4 u = h4[((size_t)m << 4) + l16];
    __half2* hp = (__half2*)&u;
    #pragma unroll
    for (int t = 0; t < 4; ++t) {
      float2 f2 = __half22float2(hp[t]);
      a[2 * t + 0] += f2.x;
      a[2 * t + 1] += f2.y;
    }
  }
  float inv = 1.0f / fmaxf((float)(end - beg), 1.0f);
  uint4 w;
  __half2* wp = (__half2*)&w;
  #pragma unroll
  for (int t = 0; t < 4; ++t)
    wp[t] = __float22half2_rn(make_float2(a[2 * t] * inv, a[2 * t + 1] * inv));
  ((uint4*)z)[((size_t)g << 4) + l16] = w;
}

// ====== decode (fp16 z): logits[e] = dot(z[a], z[b]); 16 lanes per edge, uint4/lane ======
__global__ __launch_bounds__(256) void decode16_k(const __half* __restrict__ z,
                                                  const int* __restrict__ pos,
                                                  const int* __restrict__ neg,
                                                  float* __restrict__ out, int ep) {
  int gid = blockIdx.x * blockDim.x + threadIdx.x;
  int edge = gid >> 4, l16 = gid & 15;
  if (edge >= 2 * ep) return;
  int a, b;
  if (edge < ep) { a = pos[edge];      b = pos[ep + edge]; }
  else           { int t = edge - ep; a = neg[t]; b = neg[ep + t]; }
  const uint4* z4 = (const uint4*)z;
  uint4 ua = z4[((size_t)a << 4) + l16];
  uint4 ub = z4[((size_t)b << 4) + l16];
  __half2* ha = (__half2*)&ua;
  __half2* hb = (__half2*)&ub;
  float dot = 0.f;
  #pragma unroll
  for (int t = 0; t < 4; ++t) {
    float2 fa = __half22float2(ha[t]);
    float2 fb = __half22float2(hb[t]);
    dot += fa.x * fb.x + fa.y * fb.y;
  }
  #pragma unroll
  for (int off = 8; off > 0; off >>= 1) dot += __shfl_xor(dot, off);
  if (l16 == 0) out[edge] = dot;
}

// ================= fallback path (small ws): atomic version =================
__global__ void fill_deg_k(float* __restrict__ deg, int n) {
  int i = blockIdx.x * blockDim.x + threadIdx.x;
  if (i < n) deg[i] = 1.0f;
}
__global__ void accum_deg_k(const int* __restrict__ dst, float* __restrict__ deg, int e) {
  int i = blockIdx.x * blockDim.x + threadIdx.x;
  if (i < e) atomicAdd(&deg[dst[i]], 1.0f);
}
__global__ void dinv_k(float* __restrict__ deg, int n) {
  int i = blockIdx.x * blockDim.x + threadIdx.x;
  if (i < n) deg[i] = rsqrtf(deg[i]);
}
__global__ void init_h_k(const float* __restrict__ xw, const float* __restrict__ bias,
                         const float* __restrict__ dinv, float* __restrict__ h, int n) {
  int gid = blockIdx.x * blockDim.x + threadIdx.x;
  int node = gid >> 5, c4 = gid & 31;
  if (node >= n) return;
  float di = dinv[node];
  float nm = di * di;
  float4 v = ((const float4*)(xw + (size_t)node * HH))[c4];
  float4 b = ((const float4*)bias)[c4];
  ((float4*)(h + (size_t)node * HH))[c4] =
      make_float4(b.x + nm * v.x, b.y + nm * v.y, b.z + nm * v.z, b.w + nm * v.w);
}
__global__ void scatter_k(const float* __restrict__ xw, float* __restrict__ h,
                          const float* __restrict__ dinv, const int* __restrict__ src,
                          const int* __restrict__ dst, int e) {
  int gid = blockIdx.x * blockDim.x + threadIdx.x;
  int edge = gid >> 5, lane = gid & 31;
  if (edge >= e) return;
  int s = src[edge], d = dst[edge];
  float norm = dinv[s] * dinv[d];
  float4 v = ((const float4*)(xw + (size_t)s * HH))[lane];
  float* o = h + (size_t)d * HH + lane * 4;
  atomicAdd(o + 0, norm * v.x);
  atomicAdd(o + 1, norm * v.y);
  atomicAdd(o + 2, norm * v.z);
  atomicAdd(o + 3, norm * v.w);
}
__global__ void relu_k(float4* __restrict__ h, int n4) {
  int i = blockIdx.x * blockDim.x + threadIdx.x;
  if (i < n4) {
    float4 v = h[i];
    v.x = fmaxf(v.x, 0.f); v.y = fmaxf(v.y, 0.f);
    v.z = fmaxf(v.z, 0.f); v.w = fmaxf(v.w, 0.f);
    h[i] = v;
  }
}
__global__ void pool_accum_k(const float* __restrict__ h, const int* __restrict__ dict,
                             float* __restrict__ z, float* __restrict__ cnt, int n) {
  int gid = blockIdx.x * blockDim.x + threadIdx.x;
  int node = gid >> 5, lane = gid & 31;
  if (node >= n) return;
  int d = dict[node];
  float4 v = ((const float4*)(h + (size_t)node * HH))[lane];
  float* o = z + (size_t)d * HH + lane * 4;
  atomicAdd(o + 0, v.x); atomicAdd(o + 1, v.y);
  atomicAdd(o + 2, v.z); atomicAdd(o + 3, v.w);
  if (lane == 0) atomicAdd(&cnt[d], 1.0f);
}
__global__ void pool_div_k(float* __restrict__ z, const float* __restrict__ cnt, int n) {
  int gid = blockIdx.x * blockDim.x + threadIdx.x;
  int node = gid >> 5, lane = gid & 31;
  if (node >= n) return;
  float inv = 1.0f / fmaxf(cnt[node], 1.0f);
  float4* p = (float4*)(z + (size_t)node * HH) + lane;
  float4 v = *p;
  v.x *= inv; v.y *= inv; v.z *= inv; v.w *= inv;
  *p = v;
}
__global__ void decode_k(const float* __restrict__ z, const int* __restrict__ pos,
                         const int* __restrict__ neg, float* __restrict__ out, int ep) {
  int gid = blockIdx.x * blockDim.x + threadIdx.x;
  int edge = gid >> 5, lane = gid & 31;
  if (edge >= 2 * ep) return;
  int a, b;
  if (edge < ep) { a = pos[edge];      b = pos[ep + edge]; }
  else           { a = neg[edge - ep]; b = neg[edge]; }
  const float4* za = (const float4*)(z + (size_t)a * HH);
  const float4* zb = (const float4*)(z + (size_t)b * HH);
  float4 va = za[lane], vb = zb[lane];
  float dot = va.x * vb.x + va.y * vb.y + va.z * vb.z + va.w * vb.w;
  #pragma unroll
  for (int off = 16; off > 0; off >>= 1) dot += __shfl_xor(dot, off);
  if (lane == 0) out[edge] = dot;
}

// ================= host launch =================
extern "C" void kernel_launch(void* const* d_in, const int* in_sizes, int n_in,
                              void* d_out, int out_size, void* d_ws, size_t ws_size,
                              hipStream_t stream) {
  const float* x  = (const float*)d_in[0];
  const float* W1 = (const float*)d_in[1];
  const float* b1 = (const float*)d_in[2];
  const float* W2 = (const float*)d_in[3];
  const float* b2 = (const float*)d_in[4];
  const int* ei   = (const int*)d_in[5];
  const int* dict = (const int*)d_in[6];
  const int* pe   = (const int*)d_in[7];
  const int* ne   = (const int*)d_in[8];

  const int n  = in_sizes[0] / HH;   // 100000
  const int e  = in_sizes[5] / 2;    // 1.6M
  const int ep = in_sizes[7] / 2;    // 200000
  const int* src = ei;
  const int* dst = ei + e;

  const size_t nf = (size_t)n * HH;
  const int nbkt  = (n + 255) >> 8;                 // 391
  const int CHE   = 16384, CHN = 2048;
  const int nblkE = (e + CHE - 1) / CHE;            // 98
  const int nblkN = (n + CHN - 1) / CHN;            // 49

  float*  p0     = (float*)d_ws;
  float*  bufF   = p0;
  __half* xw16   = (__half*)(p0 + nf);
  float*  dinv   = p0 + nf + nf / 2;
  int*    rowptr = (int*)(dinv + n);
  int*    tmp    = rowptr + (n + 1);
  int*    esrc   = tmp + n;
  int*    bsum   = esrc + e;
  int*    gcnt   = bsum + 256;
  int*    bktbase = gcnt + nbkt;
  size_t need = (nf + nf / 2 + n) * sizeof(float) +
                (size_t)(3 * n + 1 + e + 256 + 2 * nbkt + 1) * sizeof(int);

  int* partE   = (int*)bufF;               // e ints (6.4 MB) <= nf floats
  int* blkoffE = (int*)xw16;               // nbkt*nblkE ints <= nf halves
  int* partN   = (int*)(bufF + nf / 2);    // n ints, upper half of bufF
  int* blkoffN = partN + n;                // nbkt*nblkN ints

  const int nb    = (n + 255) / 256;
  const int nb16  = (int)(((size_t)n * 16 + 255) / 256);
  const int nb32  = (int)(((size_t)n * 32 + 255) / 256);
  const int nb64  = (int)(((size_t)n * 64 + 255) / 256);
  const int gemb  = (n + 63) / 64;
  const int deb16 = (int)(((size_t)2 * ep * 16 + 255) / 256);

  bool fast = (ws_size >= need) && (nbkt <= 512) && (n < (1 << 23)) &&
              ((size_t)e <= nf) && ((size_t)nbkt * nblkE * 2 <= nf) &&
              ((size_t)(n + (size_t)nbkt * nblkN) * 2 <= nf);

  if (fast) {
    // ---- edge CSR (by dst) + dinv: bucketed 2-phase sort (packed records) ----
    hipMemsetAsync(gcnt, 0, (size_t)nbkt * sizeof(int), stream);
    part_count_k<<<nblkE, 256, 0, stream>>>(dst, e, CHE, nbkt, nblkE, gcnt, blkoffE);
    scan_bkt_k<<<1, 512, 0, stream>>>(gcnt, bktbase, nbkt, e);
    part_scatter_k<<<nblkE, 256, 0, stream>>>(src, dst, e, CHE, nbkt, nblkE, bktbase, blkoffE, partE);
    bucket_csr_k<<<nbkt, 256, 0, stream>>>(partE, bktbase, rowptr, dinv, esrc, n, e, nbkt);

    // ---- conv1: xw16 = fp16(dinv * x@W1);  h1 fp16 in lower bufF ----
    gemm128_v5<float, true><<<gemb, 256, 0, stream>>>(x, W1, dinv, xw16, n);
    __half* h1_16 = (__half*)bufF;
    gather16_k<<<nb64, 256, 0, stream>>>(xw16, rowptr, esrc, dinv, b1, h1_16, n);
    // ---- conv2: xw16 = fp16(dinv * h1@W2);  h2 fp16 overwrites h1 region ----
    gemm128_v5<__half, true><<<gemb, 256, 0, stream>>>(h1_16, W2, dinv, xw16, n);
    __half* h2_16 = (__half*)bufF;
    gather16_k<<<nb64, 256, 0, stream>>>(xw16, rowptr, esrc, dinv, b2, h2_16, n);
    // xw16 dead -> becomes z; upper half of bufF free -> partN

    // ---- node CSR (by dict): bucketed sort (packed records, chunk=2048) ----
    hipMemsetAsync(gcnt, 0, (size_t)nbkt * sizeof(int), stream);
    part_count_k<<<nblkN, 256, 0, stream>>>(dict, n, CHN, nbkt, nblkN, gcnt, blkoffN);
    scan_bkt_k<<<1, 512, 0, stream>>>(gcnt, bktbase, nbkt, n);
    part_scatter_idx_k<<<nblkN, 256, 0, stream>>>(dict, n, CHN, nbkt, nblkN, bktbase, blkoffN, partN);
    bucket_csr_k<<<nbkt, 256, 0, stream>>>(partN, bktbase, rowptr, nullptr, esrc, n, n, nbkt);
    // rowptr = group rowptr, esrc = nodelist

    // ---- pool (fp16 z) then plain dot decode ----
    __half* z16 = xw16;
    pool16_k<<<nb16, 256, 0, stream>>>(h2_16, rowptr, esrc, z16, n);
    decode16_k<<<deb16, 256, 0, stream>>>(z16, pe, ne, (float*)d_out, ep);
  } else {
    // ---- fallback: atomic path (bufA, bufB, dinv2, cnt), all fp32 ----
    float* bufA  = (float*)d_ws;
    float* bufB  = bufA + nf;
    float* dinv2 = bufB + nf;
    float* cnt   = dinv2 + n;
    fill_deg_k<<<nb, 256, 0, stream>>>(dinv2, n);
    accum_deg_k<<<(e + 255) / 256, 256, 0, stream>>>(dst, dinv2, e);
    dinv_k<<<nb, 256, 0, stream>>>(dinv2, n);

    gemm128_v5<float, false><<<gemb, 256, 0, stream>>>(x, W1, nullptr, bufA, n);
    init_h_k<<<nb32, 256, 0, stream>>>(bufA, b1, dinv2, bufB, n);
    scatter_k<<<(int)(((size_t)e * 32 + 255) / 256), 256, 0, stream>>>(bufA, bufB, dinv2, src, dst, e);
    relu_k<<<nb32, 256, 0, stream>>>((float4*)bufB, n * 32);

    gemm128_v5<float, false><<<gemb, 256, 0, stream>>>(bufB, W2, nullptr, bufA, n);
    init_h_k<<<nb32, 256, 0, stream>>>(bufA, b2, dinv2, bufB, n);
    scatter_k<<<(int)(((size_t)e * 32 + 255) / 256), 256, 0, stream>>>(bufA, bufB, dinv2, src, dst, e);
    relu_k<<<nb32, 256, 0, stream>>>((float4*)bufB, n * 32);

    hipMemsetAsync(bufA, 0, nf * sizeof(float), stream);
    hipMemsetAsync(cnt, 0, (size_t)n * sizeof(float), stream);
    pool_accum_k<<<nb32, 256, 0, stream>>>(bufB, dict, bufA, cnt, n);
    pool_div_k<<<nb32, 256, 0, stream>>>(bufA, cnt, n);
    decode_k<<<(int)(((size_t)2 * ep * 32 + 255) / 256), 256, 0, stream>>>(
        bufA, pe, ne, (float*)d_out, ep);
  }
}